// Round 3
// baseline (139.681 us; speedup 1.0000x reference)
//
#include <hip/hip_runtime.h>
#include <hip/hip_fp16.h>

#define NB 4
#define NH 12
#define DHD 64
#define LQ 512
#define LK 512
#define DM 768

typedef __attribute__((ext_vector_type(4))) _Float16 f16x4;
typedef __attribute__((ext_vector_type(8))) _Float16 f16x8;
typedef __attribute__((ext_vector_type(4))) float f32x4;

// global_load_lds width=16: linear LDS dest (wave-uniform base + lane*16),
// per-lane global source. Explicit addrspace casts -> proper addrspacecast.
typedef __attribute__((address_space(1))) const unsigned int ga_uint;
typedef __attribute__((address_space(3))) unsigned int lds_uint;
__device__ static inline void gload_lds16(const void* g, void* l) {
    __builtin_amdgcn_global_load_lds((ga_uint*)g, (lds_uint*)l, 16, 0, 0);
}

// ---------------------------------------------------------------------------
// Kernel 0 (prep): blocks 0..431 transpose+convert Wq/Wk/Wv -> WT f16
// [mat][n][k]; block 432 computes the 3x64 LN tables (lnK pre-scaled by 8).
// ---------------------------------------------------------------------------
__global__ __launch_bounds__(256) void prep_kernel(
    const float* __restrict__ Wq, const float* __restrict__ Wk,
    const float* __restrict__ Wv,
    const float* __restrict__ dpk, const float* __restrict__ dpv,
    const float* __restrict__ gk, const float* __restrict__ bk,
    const float* __restrict__ gv, const float* __restrict__ bv,
    _Float16* __restrict__ WT, float* __restrict__ lnK, float* __restrict__ lnV)
{
    const int bid = blockIdx.x, t = threadIdx.x;
    if (bid < 432) {
        __shared__ float sT[64][65];
        int mat = bid / 144, tile = bid % 144;
        int k0 = (tile / 12) * 64, n0 = (tile % 12) * 64;
        const float* W = (mat == 0) ? Wq : (mat == 1) ? Wk : Wv;
        #pragma unroll
        for (int p = 0; p < 4; ++p) {
            int idx = t + p * 256;
            int ki = idx >> 4, nj = (idx & 15) * 4;
            float4 wv = *(const float4*)&W[(size_t)(k0 + ki) * DM + n0 + nj];
            sT[ki][nj + 0] = wv.x; sT[ki][nj + 1] = wv.y;
            sT[ki][nj + 2] = wv.z; sT[ki][nj + 3] = wv.w;
        }
        __syncthreads();
        _Float16* dst = WT + (size_t)mat * DM * DM;
        #pragma unroll
        for (int p = 0; p < 4; ++p) {
            int idx = t + p * 256;
            int nr = idx >> 4, kj = (idx & 15) * 4;
            f16x4 hv = { (_Float16)sT[kj + 0][nr], (_Float16)sT[kj + 1][nr],
                         (_Float16)sT[kj + 2][nr], (_Float16)sT[kj + 3][nr] };
            *(f16x4*)&dst[(size_t)(n0 + nr) * DM + k0 + kj] = hv;
        }
    } else if (t < 64) {
        int lane = t;
        for (int r = 0; r < 3; ++r) {
            {
                float x = dpk[r * DHD + lane];
                float s = x;
                #pragma unroll
                for (int o = 1; o < 64; o <<= 1) s += __shfl_xor(s, o);
                float mu = s * (1.0f / 64.0f);
                float d = x - mu;
                float v = d * d;
                #pragma unroll
                for (int o = 1; o < 64; o <<= 1) v += __shfl_xor(v, o);
                lnK[r * DHD + lane] =
                    (d * rsqrtf(v * (1.0f / 64.0f) + 1e-5f) * gk[lane] + bk[lane]) * 8.0f;
            }
            {
                float x = dpv[r * DHD + lane];
                float s = x;
                #pragma unroll
                for (int o = 1; o < 64; o <<= 1) s += __shfl_xor(s, o);
                float mu = s * (1.0f / 64.0f);
                float d = x - mu;
                float v = d * d;
                #pragma unroll
                for (int o = 1; o < 64; o <<= 1) v += __shfl_xor(v, o);
                lnV[r * DHD + lane] =
                    d * rsqrtf(v * (1.0f / 64.0f) + 1e-5f) * gv[lane] + bv[lane];
            }
        }
    }
}

// ---------------------------------------------------------------------------
// Kernel 1: QKV projection, fp16 MFMA. Tile 64(M)x96(N), K-step 64, 12 iters,
// grid 32x24 = 768 = exactly 3 blocks/CU. Waves 2m x 2n, acc[2][3].
// B staging via global_load_lds width=16 into LINEAR LDS with XOR-swizzled
// source + XOR-swizzled ds_read_b128 (rule: both-sides-or-neither).
// A staged fp32->f16 (stride 72 = free 2-way). Q scaled 1/8 in epilogue.
// ---------------------------------------------------------------------------
__global__ __launch_bounds__(256) void qkv_mfma(
    const float* __restrict__ hidden, const float* __restrict__ context,
    const _Float16* __restrict__ WT,
    const float* __restrict__ bq, const float* __restrict__ bk,
    const float* __restrict__ bv,
    _Float16* __restrict__ Qh, _Float16* __restrict__ Kh,
    _Float16* __restrict__ VTh)
{
    __shared__ __align__(16) char smem[21504];
    _Float16 (*sA)[72]  = (_Float16(*)[72])smem;             // 64x72  =  9216 B
    char* sB            = smem + 9216;                       // 96x128 = 12288 B linear
    _Float16 (*sC)[104] = (_Float16(*)[104])smem;            // 64x104 = 13312 B
    _Float16 (*sCV)[72] = (_Float16(*)[72])smem;             // 96x72  = 13824 B -> but
    // NOTE: sCV needs 13824 B; smem is 21504 B so it fits (epilogue only).

    const int t = threadIdx.x;
    const int w = t >> 6, lane = t & 63, g = lane >> 4, c16 = lane & 15;
    const int wm = w >> 1, wn = w & 1;
    const int mat = blockIdx.y / 8, nt0 = blockIdx.y % 8;
    const int m0 = blockIdx.x * 64, n0 = nt0 * 96;
    const float* X     = (mat == 0) ? hidden : context;
    const _Float16* Wt = WT + (size_t)mat * DM * DM;
    const float* bias  = (mat == 0) ? bq : (mat == 1) ? bk : bv;

    // per-lane source swizzle for B staging (constant across kt)
    const int srow = (lane >> 3);                 // row within 8-row chunk
    const int sunit = (lane & 7) ^ srow;          // 16B unit, XOR-swizzled

    f32x4 acc[2][3];
    #pragma unroll
    for (int mt = 0; mt < 2; ++mt)
        #pragma unroll
        for (int nt = 0; nt < 3; ++nt) acc[mt][nt] = (f32x4){0.f, 0.f, 0.f, 0.f};

    for (int kt = 0; kt < 12; ++kt) {
        __syncthreads();
        // A: 64 rows x 64 k, fp32 -> f16 convert during staging
        #pragma unroll
        for (int p = 0; p < 4; ++p) {
            int idx = t + p * 256;
            int row = idx >> 4, c4 = idx & 15;
            float4 xv = *(const float4*)&X[(size_t)(m0 + row) * DM + kt * 64 + c4 * 4];
            f16x4 hv = { (_Float16)xv.x, (_Float16)xv.y,
                         (_Float16)xv.z, (_Float16)xv.w };
            *(f16x4*)&sA[row][c4 * 4] = hv;
        }
        // B: 96 n-rows x 128 B, 12 chunks of 8 rows; wave w stages chunks 3w..3w+2
        #pragma unroll
        for (int cc = 0; cc < 3; ++cc) {
            int chunk = w * 3 + cc;
            int row = chunk * 8 + srow;
            gload_lds16(
                (const char*)&Wt[(size_t)(n0 + row) * DM + kt * 64] + sunit * 16,
                sB + chunk * 1024);
        }
        __syncthreads();
        #pragma unroll
        for (int kh = 0; kh < 2; ++kh) {
            f16x8 af[2], bf[3];
            #pragma unroll
            for (int mt = 0; mt < 2; ++mt)
                af[mt] = *(const f16x8*)&sA[wm * 32 + mt * 16 + c16][kh * 32 + 8 * g];
            #pragma unroll
            for (int nt = 0; nt < 3; ++nt) {
                int rn = wn * 48 + nt * 16 + c16;
                int boff = (rn * 128 + kh * 64 + g * 16) ^ ((rn & 7) << 4);
                bf[nt] = *(const f16x8*)(sB + boff);
            }
            #pragma unroll
            for (int mt = 0; mt < 2; ++mt)
                #pragma unroll
                for (int nt = 0; nt < 3; ++nt)
                    acc[mt][nt] = __builtin_amdgcn_mfma_f32_16x16x32_f16(
                        af[mt], bf[nt], acc[mt][nt], 0, 0, 0);
        }
    }

    const float sc = (mat == 0) ? 0.125f : 1.0f;
    float bb[3];
    #pragma unroll
    for (int nt = 0; nt < 3; ++nt)
        bb[nt] = bias[n0 + wn * 48 + nt * 16 + c16] * sc;
    __syncthreads();

    const int bbat = m0 >> 9, l0 = m0 & 511;
    if (mat < 2) {
        #pragma unroll
        for (int mt = 0; mt < 2; ++mt)
            #pragma unroll
            for (int nt = 0; nt < 3; ++nt)
                #pragma unroll
                for (int r = 0; r < 4; ++r)
                    sC[wm * 32 + mt * 16 + 4 * g + r][wn * 48 + nt * 16 + c16] =
                        (_Float16)(acc[mt][nt][r] * sc + bb[nt]);
        __syncthreads();
        _Float16* dst = (mat == 0) ? Qh : Kh;
        int row = t >> 2, qc = t & 3;
        #pragma unroll
        for (int j = 0; j < 3; ++j) {
            int col = qc * 24 + j * 8;
            int hd = (n0 + col) >> 6, d8 = (n0 + col) & 63;
            *(f16x8*)&dst[((size_t)(bbat * NH + hd) * LQ + l0 + row) * DHD + d8] =
                *(const f16x8*)&sC[row][col];
        }
    } else {
        #pragma unroll
        for (int mt = 0; mt < 2; ++mt)
            #pragma unroll
            for (int nt = 0; nt < 3; ++nt)
                #pragma unroll
                for (int r = 0; r < 4; ++r)
                    sCV[wn * 48 + nt * 16 + c16][wm * 32 + mt * 16 + 4 * g + r] =
                        (_Float16)(acc[mt][nt][r] + bb[nt]);
        __syncthreads();
        #pragma unroll
        for (int p = 0; p < 3; ++p) {
            int idx = t + p * 256;
            int n = idx >> 3, c8 = idx & 7;
            *(f16x8*)&VTh[((size_t)(bbat * NH + ((n0 + n) >> 6)) * DHD + ((n0 + n) & 63)) * LK
                          + l0 + c8 * 8] = *(const f16x8*)&sCV[n][c8 * 8];
        }
    }
}

// ---------------------------------------------------------------------------
// Kernel 2: attention, fp16 MFMA, q-tile 32 — verbatim R1-passing version.
// Arc table 2-bit packed (pitch 33, broadcast reads); bucket softmax sums;
// P in LDS f16; V frags from global.
// ---------------------------------------------------------------------------
__global__ __launch_bounds__(256) void attn_mfma(
    const _Float16* __restrict__ Qh, const _Float16* __restrict__ Kh,
    const _Float16* __restrict__ VTh, const float* __restrict__ maskp,
    const int* __restrict__ garc, const float* __restrict__ lnK,
    const float* __restrict__ lnV, float* __restrict__ outp)
{
    __shared__ __align__(16) _Float16 sP[32][520];
    __shared__ unsigned int sArcW[32 * 33];
    __shared__ float sTb[32][4];
    __shared__ float sMax[4][32];
    __shared__ float sStat[4][32][4];
    __shared__ float sFin[32][4];

    const int t = threadIdx.x;
    const int w = t >> 6, lane = t & 63, g = lane >> 4, c16 = lane & 15;
    const int bx = blockIdx.x;
    const int qt = bx & 15, h = (bx >> 4) % NH, b = bx / (16 * NH);
    const int q0 = qt * 32;
    const int kw = w * 128;

    const _Float16* Qb = Qh + ((size_t)(b * NH + h) * LQ) * DHD;
    const _Float16* Kb = Kh + ((size_t)(b * NH + h) * LK) * DHD;
    const _Float16* Vb = VTh + ((size_t)(b * NH + h) * DHD) * LK;

    const int* garcRow = garc + ((size_t)(b * LQ + q0)) * LK;
    #pragma unroll
    for (int p = 0; p < 4; ++p) {
        int idx = t + p * 256;
        int row = idx >> 5, wd = idx & 31;
        const int4* src = (const int4*)&garcRow[idx * 16];
        unsigned int u = 0;
        #pragma unroll
        for (int j = 0; j < 4; ++j) {
            int4 a4 = src[j];
            u |= (unsigned int)a4.x << (j * 8 + 0);
            u |= (unsigned int)a4.y << (j * 8 + 2);
            u |= (unsigned int)a4.z << (j * 8 + 4);
            u |= (unsigned int)a4.w << (j * 8 + 6);
        }
        sArcW[row * 33 + wd] = u;
    }
    if (t < 192) {
        int q = t / 6, rem = t % 6, rr = rem >> 1, part = rem & 1;
        const _Float16* qp = Qb + (size_t)(q0 + q) * DHD + part * 32;
        const float* lp = lnK + rr * 64 + part * 32;
        float a = 0.f;
        #pragma unroll
        for (int j = 0; j < 4; ++j) {
            f16x8 qv = *(const f16x8*)&qp[j * 8];
            float4 l0 = *(const float4*)&lp[j * 8];
            float4 l1 = *(const float4*)&lp[j * 8 + 4];
            a += (float)qv[0] * l0.x + (float)qv[1] * l0.y
               + (float)qv[2] * l0.z + (float)qv[3] * l0.w
               + (float)qv[4] * l1.x + (float)qv[5] * l1.y
               + (float)qv[6] * l1.z + (float)qv[7] * l1.w;
        }
        a += __shfl_xor(a, 1);
        if (part == 0) sTb[q][rr] = a;
    }
    f16x8 qa[2][2];
    #pragma unroll
    for (int qg = 0; qg < 2; ++qg) {
        qa[qg][0] = *(const f16x8*)&Qb[(q0 + 16 * qg + c16) * DHD + 8 * g];
        qa[qg][1] = *(const f16x8*)&Qb[(q0 + 16 * qg + c16) * DHD + 32 + 8 * g];
    }
    __syncthreads();

    f32x4 c[8][2];
    unsigned int aPk[2][2] = {{0u, 0u}, {0u, 0u}};
    float rm[2][4];
    const int sh = c16 * 2;
    #pragma unroll
    for (int qg = 0; qg < 2; ++qg)
        #pragma unroll
        for (int r = 0; r < 4; ++r) rm[qg][r] = -1e30f;
    #pragma unroll
    for (int tt = 0; tt < 8; ++tt) {
        int kg = kw + tt * 16 + c16;
        f16x8 kb0 = *(const f16x8*)&Kb[kg * DHD + 8 * g];
        f16x8 kb1 = *(const f16x8*)&Kb[kg * DHD + 32 + 8 * g];
        float mv = maskp[b * LK + kg];
        const int wb = w * 8 + tt;
        #pragma unroll
        for (int qg = 0; qg < 2; ++qg) {
            f32x4 s = (f32x4){0.f, 0.f, 0.f, 0.f};
            s = __builtin_amdgcn_mfma_f32_16x16x32_f16(qa[qg][0], kb0, s, 0, 0, 0);
            s = __builtin_amdgcn_mfma_f32_16x16x32_f16(qa[qg][1], kb1, s, 0, 0, 0);
            #pragma unroll
            for (int r = 0; r < 4; ++r) {
                int qrow = 16 * qg + 4 * g + r;
                unsigned int a = (sArcW[qrow * 33 + wb] >> sh) & 3u;
                aPk[qg][tt >> 2] |= a << ((tt & 3) * 8 + 2 * r);
                float sv = s[r] + sTb[qrow][a] + mv;
                s[r] = sv;
                rm[qg][r] = fmaxf(rm[qg][r], sv);
            }
            c[tt][qg] = s;
        }
    }

    #pragma unroll
    for (int qg = 0; qg < 2; ++qg)
        #pragma unroll
        for (int r = 0; r < 4; ++r) {
            float m = rm[qg][r];
            m = fmaxf(m, __shfl_xor(m, 1));
            m = fmaxf(m, __shfl_xor(m, 2));
            m = fmaxf(m, __shfl_xor(m, 4));
            m = fmaxf(m, __shfl_xor(m, 8));
            rm[qg][r] = m;
        }
    if (c16 == 0)
        #pragma unroll
        for (int qg = 0; qg < 2; ++qg)
            #pragma unroll
            for (int r = 0; r < 4; ++r) sMax[w][16 * qg + 4 * g + r] = rm[qg][r];
    __syncthreads();
    float Mr[2][4];
    #pragma unroll
    for (int qg = 0; qg < 2; ++qg)
        #pragma unroll
        for (int r = 0; r < 4; ++r) {
            int q = 16 * qg + 4 * g + r;
            Mr[qg][r] = fmaxf(fmaxf(sMax[0][q], sMax[1][q]),
                              fmaxf(sMax[2][q], sMax[3][q]));
        }

    float b0s[2][4], b1s[2][4], b2s[2][4];
    #pragma unroll
    for (int qg = 0; qg < 2; ++qg)
        #pragma unroll
        for (int r = 0; r < 4; ++r) {
            b0s[qg][r] = 0.f; b1s[qg][r] = 0.f; b2s[qg][r] = 0.f;
        }
    #pragma unroll
    for (int tt = 0; tt < 8; ++tt) {
        int kg = kw + tt * 16 + c16;
        #pragma unroll
        for (int qg = 0; qg < 2; ++qg)
            #pragma unroll
            for (int r = 0; r < 4; ++r) {
                float e = __expf(c[tt][qg][r] - Mr[qg][r]);
                unsigned int a = (aPk[qg][tt >> 2] >> ((tt & 3) * 8 + 2 * r)) & 3u;
                b0s[qg][r] += (a == 0u) ? e : 0.f;
                b1s[qg][r] += (a == 1u) ? e : 0.f;
                b2s[qg][r] += (a == 2u) ? e : 0.f;
                sP[16 * qg + 4 * g + r][kg] = (_Float16)e;
            }
    }
    #pragma unroll
    for (int qg = 0; qg < 2; ++qg)
        #pragma unroll
        for (int r = 0; r < 4; ++r) {
            #pragma unroll
            for (int o = 1; o < 16; o <<= 1) {
                b0s[qg][r] += __shfl_xor(b0s[qg][r], o);
                b1s[qg][r] += __shfl_xor(b1s[qg][r], o);
                b2s[qg][r] += __shfl_xor(b2s[qg][r], o);
            }
        }
    if (c16 == 0)
        #pragma unroll
        for (int qg = 0; qg < 2; ++qg)
            #pragma unroll
            for (int r = 0; r < 4; ++r) {
                float4 v = make_float4(b0s[qg][r], b1s[qg][r], b2s[qg][r], 0.f);
                *(float4*)&sStat[w][16 * qg + 4 * g + r][0] = v;
            }
    __syncthreads();
    if (t < 32) {
        float4 tot = make_float4(0.f, 0.f, 0.f, 0.f);
        #pragma unroll
        for (int ww = 0; ww < 4; ++ww) {
            float4 v = *(const float4*)&sStat[ww][t][0];
            tot.x += v.x; tot.y += v.y; tot.z += v.z;
        }
        sFin[t][0] = 1.0f / (tot.x + tot.y + tot.z);
        sFin[t][1] = tot.x; sFin[t][2] = tot.y; sFin[t][3] = tot.z;
    }

    f32x4 o[2] = {(f32x4){0.f, 0.f, 0.f, 0.f}, (f32x4){0.f, 0.f, 0.f, 0.f}};
    const _Float16* vrow = Vb + (size_t)(w * 16 + c16) * LK;
    #pragma unroll
    for (int ktile = 0; ktile < 16; ++ktile) {
        f16x8 vb = *(const f16x8*)&vrow[ktile * 32 + 8 * g];
        #pragma unroll
        for (int qg = 0; qg < 2; ++qg) {
            f16x8 pa = *(const f16x8*)&sP[16 * qg + c16][ktile * 32 + 8 * g];
            o[qg] = __builtin_amdgcn_mfma_f32_16x16x32_f16(pa, vb, o[qg], 0, 0, 0);
        }
    }
    __syncthreads();

    int d = w * 16 + c16;
    float lv0 = lnV[d], lv1 = lnV[64 + d], lv2 = lnV[128 + d];
    #pragma unroll
    for (int qg = 0; qg < 2; ++qg)
        #pragma unroll
        for (int r = 0; r < 4; ++r) {
            int q = 16 * qg + 4 * g + r;
            float4 st = *(const float4*)&sFin[q][0];
            float val = (o[qg][r] + st.y * lv0 + st.z * lv1 + st.w * lv2) * st.x;
            outp[((size_t)(b * LQ + q0 + q)) * DM + h * DHD + d] = val;
        }
}

// ---------------------------------------------------------------------------
extern "C" void kernel_launch(void* const* d_in, const int* in_sizes, int n_in,
                              void* d_out, int out_size, void* d_ws, size_t ws_size,
                              hipStream_t stream) {
    const float* hidden  = (const float*)d_in[0];
    const float* context = (const float*)d_in[1];
    const float* mask    = (const float*)d_in[2];
    const int*   garc    = (const int*)d_in[3];
    const float* Wq = (const float*)d_in[4];
    const float* bq = (const float*)d_in[5];
    const float* Wk = (const float*)d_in[6];
    const float* bk = (const float*)d_in[7];
    const float* Wv = (const float*)d_in[8];
    const float* bv = (const float*)d_in[9];
    const float* dpk  = (const float*)d_in[10];
    const float* dpv  = (const float*)d_in[11];
    const float* lnkg = (const float*)d_in[12];
    const float* lnkb = (const float*)d_in[13];
    const float* lnvg = (const float*)d_in[14];
    const float* lnvb = (const float*)d_in[15];
    float* out = (float*)d_out;

    const size_t perT = (size_t)NB * NH * LQ * DHD;   // 1,572,864 halves
    _Float16* Qh  = (_Float16*)d_ws;
    _Float16* Kh  = Qh + perT;
    _Float16* VTh = Kh + perT;
    _Float16* WT  = VTh + perT;                        // 3*768*768 halves
    float* lnK = (float*)(WT + (size_t)3 * DM * DM);
    float* lnV = lnK + 192;

    prep_kernel<<<433, 256, 0, stream>>>(Wq, Wk, Wv, dpk, dpv,
                                         lnkg, lnkb, lnvg, lnvb, WT, lnK, lnV);
    qkv_mfma<<<dim3(32, 24), 256, 0, stream>>>(hidden, context, WT,
                                               bq, bk, bv, Qh, Kh, VTh);
    attn_mfma<<<768, 256, 0, stream>>>(Qh, Kh, VTh, mask, garc, lnK, lnV, out);
}

// Round 4
// 137.921 us; speedup vs baseline: 1.0128x; 1.0128x over previous
//
#include <hip/hip_runtime.h>
#include <hip/hip_fp16.h>

#define NB 4
#define NH 12
#define DHD 64
#define LQ 512
#define LK 512
#define DM 768

typedef __attribute__((ext_vector_type(4))) _Float16 f16x4;
typedef __attribute__((ext_vector_type(8))) _Float16 f16x8;
typedef __attribute__((ext_vector_type(4))) float f32x4;

// global_load_lds width=16: linear LDS dest (wave-uniform base + lane*16),
// per-lane global source.
typedef __attribute__((address_space(1))) const unsigned int ga_uint;
typedef __attribute__((address_space(3))) unsigned int lds_uint;
__device__ static inline void gload_lds16(const void* g, void* l) {
    __builtin_amdgcn_global_load_lds((ga_uint*)g, (lds_uint*)l, 16, 0, 0);
}

// ---------------------------------------------------------------------------
// Kernel 0 (prep): blocks 0..431 transpose+convert Wq/Wk/Wv -> WT f16
// [mat][n][k]; block 432 computes the 3x64 LN tables (lnK pre-scaled by 8).
// ---------------------------------------------------------------------------
__global__ __launch_bounds__(256) void prep_kernel(
    const float* __restrict__ Wq, const float* __restrict__ Wk,
    const float* __restrict__ Wv,
    const float* __restrict__ dpk, const float* __restrict__ dpv,
    const float* __restrict__ gk, const float* __restrict__ bk,
    const float* __restrict__ gv, const float* __restrict__ bv,
    _Float16* __restrict__ WT, float* __restrict__ lnK, float* __restrict__ lnV)
{
    const int bid = blockIdx.x, t = threadIdx.x;
    if (bid < 432) {
        __shared__ float sT[64][65];
        int mat = bid / 144, tile = bid % 144;
        int k0 = (tile / 12) * 64, n0 = (tile % 12) * 64;
        const float* W = (mat == 0) ? Wq : (mat == 1) ? Wk : Wv;
        #pragma unroll
        for (int p = 0; p < 4; ++p) {
            int idx = t + p * 256;
            int ki = idx >> 4, nj = (idx & 15) * 4;
            float4 wv = *(const float4*)&W[(size_t)(k0 + ki) * DM + n0 + nj];
            sT[ki][nj + 0] = wv.x; sT[ki][nj + 1] = wv.y;
            sT[ki][nj + 2] = wv.z; sT[ki][nj + 3] = wv.w;
        }
        __syncthreads();
        _Float16* dst = WT + (size_t)mat * DM * DM;
        #pragma unroll
        for (int p = 0; p < 4; ++p) {
            int idx = t + p * 256;
            int nr = idx >> 4, kj = (idx & 15) * 4;
            f16x4 hv = { (_Float16)sT[kj + 0][nr], (_Float16)sT[kj + 1][nr],
                         (_Float16)sT[kj + 2][nr], (_Float16)sT[kj + 3][nr] };
            *(f16x4*)&dst[(size_t)(n0 + nr) * DM + k0 + kj] = hv;
        }
    } else if (t < 64) {
        int lane = t;
        for (int r = 0; r < 3; ++r) {
            {
                float x = dpk[r * DHD + lane];
                float s = x;
                #pragma unroll
                for (int o = 1; o < 64; o <<= 1) s += __shfl_xor(s, o);
                float mu = s * (1.0f / 64.0f);
                float d = x - mu;
                float v = d * d;
                #pragma unroll
                for (int o = 1; o < 64; o <<= 1) v += __shfl_xor(v, o);
                lnK[r * DHD + lane] =
                    (d * rsqrtf(v * (1.0f / 64.0f) + 1e-5f) * gk[lane] + bk[lane]) * 8.0f;
            }
            {
                float x = dpv[r * DHD + lane];
                float s = x;
                #pragma unroll
                for (int o = 1; o < 64; o <<= 1) s += __shfl_xor(s, o);
                float mu = s * (1.0f / 64.0f);
                float d = x - mu;
                float v = d * d;
                #pragma unroll
                for (int o = 1; o < 64; o <<= 1) v += __shfl_xor(v, o);
                lnV[r * DHD + lane] =
                    d * rsqrtf(v * (1.0f / 64.0f) + 1e-5f) * gv[lane] + bv[lane];
            }
        }
    }
}

// ---------------------------------------------------------------------------
// Kernel 1: QKV projection, fp16 MFMA. Tile 64(M)x96(N), K-step 128 (was 64):
// 6 iters x 2 barriers = 12 full drains per block instead of 24 — targeting
// the barrier-drain stall (every __syncthreads forces vmcnt(0)+lgkmcnt(0) for
// all resident waves). Same MFMA total (144/wave). LDS 41984 B -> still
// exactly 3 blocks/CU. B staged via global_load_lds w=16, 4-row/1KB chunks,
// XOR-swizzled source (unit ^= row&15) + matching XOR on ds_read_b128.
// ---------------------------------------------------------------------------
__global__ __launch_bounds__(256) void qkv_mfma(
    const float* __restrict__ hidden, const float* __restrict__ context,
    const _Float16* __restrict__ WT,
    const float* __restrict__ bq, const float* __restrict__ bk,
    const float* __restrict__ bv,
    _Float16* __restrict__ Qh, _Float16* __restrict__ Kh,
    _Float16* __restrict__ VTh)
{
    __shared__ __align__(16) char smem[41984];
    _Float16 (*sA)[136] = (_Float16(*)[136])smem;            // 64x136 = 17408 B
    char* sB            = smem + 17408;                      // 96x256 = 24576 B linear
    _Float16 (*sC)[104] = (_Float16(*)[104])smem;            // 64x104 = 13312 B (epilogue)
    _Float16 (*sCV)[72] = (_Float16(*)[72])smem;             // 96x72  = 13824 B (epilogue)

    const int t = threadIdx.x;
    const int w = t >> 6, lane = t & 63, g = lane >> 4, c16 = lane & 15;
    const int wm = w >> 1, wn = w & 1;
    const int mat = blockIdx.y / 8, nt0 = blockIdx.y % 8;
    const int m0 = blockIdx.x * 64, n0 = nt0 * 96;
    const float* X     = (mat == 0) ? hidden : context;
    const _Float16* Wt = WT + (size_t)mat * DM * DM;
    const float* bias  = (mat == 0) ? bq : (mat == 1) ? bk : bv;

    // B staging geometry: chunk = 4 rows x 256 B = 1024 B = one wave gload_lds16.
    const int srow4 = lane >> 4;                  // row within 4-row chunk
    const int u16   = lane & 15;                  // 16B unit within 256B row

    f32x4 acc[2][3];
    #pragma unroll
    for (int mt = 0; mt < 2; ++mt)
        #pragma unroll
        for (int nt = 0; nt < 3; ++nt) acc[mt][nt] = (f32x4){0.f, 0.f, 0.f, 0.f};

    for (int kt = 0; kt < 6; ++kt) {
        __syncthreads();
        // A: 64 rows x 128 k, fp32 -> f16 convert during staging (8 passes)
        #pragma unroll
        for (int p = 0; p < 8; ++p) {
            int idx = t + p * 256;
            int row = idx >> 5, c4 = idx & 31;
            float4 xv = *(const float4*)&X[(size_t)(m0 + row) * DM + kt * 128 + c4 * 4];
            f16x4 hv = { (_Float16)xv.x, (_Float16)xv.y,
                         (_Float16)xv.z, (_Float16)xv.w };
            *(f16x4*)&sA[row][c4 * 4] = hv;
        }
        // B: 96 rows x 256 B = 24 chunks; wave w stages chunks 6w..6w+5
        #pragma unroll
        for (int cc = 0; cc < 6; ++cc) {
            int chunk = w * 6 + cc;
            int row = chunk * 4 + srow4;
            int gu = u16 ^ (row & 15);            // inverse of read-side XOR
            gload_lds16(
                (const char*)&Wt[(size_t)(n0 + row) * DM + kt * 128] + gu * 16,
                sB + chunk * 1024);
        }
        __syncthreads();
        #pragma unroll
        for (int kh = 0; kh < 4; ++kh) {
            f16x8 af[2], bf[3];
            #pragma unroll
            for (int mt = 0; mt < 2; ++mt)
                af[mt] = *(const f16x8*)&sA[wm * 32 + mt * 16 + c16][kh * 32 + 8 * g];
            #pragma unroll
            for (int nt = 0; nt < 3; ++nt) {
                int rn = wn * 48 + nt * 16 + c16;
                int unit = (kh * 4 + g) ^ (rn & 15);
                bf[nt] = *(const f16x8*)(sB + rn * 256 + unit * 16);
            }
            #pragma unroll
            for (int mt = 0; mt < 2; ++mt)
                #pragma unroll
                for (int nt = 0; nt < 3; ++nt)
                    acc[mt][nt] = __builtin_amdgcn_mfma_f32_16x16x32_f16(
                        af[mt], bf[nt], acc[mt][nt], 0, 0, 0);
        }
    }

    const float sc = (mat == 0) ? 0.125f : 1.0f;
    float bb[3];
    #pragma unroll
    for (int nt = 0; nt < 3; ++nt)
        bb[nt] = bias[n0 + wn * 48 + nt * 16 + c16] * sc;
    __syncthreads();

    const int bbat = m0 >> 9, l0 = m0 & 511;
    if (mat < 2) {
        #pragma unroll
        for (int mt = 0; mt < 2; ++mt)
            #pragma unroll
            for (int nt = 0; nt < 3; ++nt)
                #pragma unroll
                for (int r = 0; r < 4; ++r)
                    sC[wm * 32 + mt * 16 + 4 * g + r][wn * 48 + nt * 16 + c16] =
                        (_Float16)(acc[mt][nt][r] * sc + bb[nt]);
        __syncthreads();
        _Float16* dst = (mat == 0) ? Qh : Kh;
        int row = t >> 2, qc = t & 3;
        #pragma unroll
        for (int j = 0; j < 3; ++j) {
            int col = qc * 24 + j * 8;
            int hd = (n0 + col) >> 6, d8 = (n0 + col) & 63;
            *(f16x8*)&dst[((size_t)(bbat * NH + hd) * LQ + l0 + row) * DHD + d8] =
                *(const f16x8*)&sC[row][col];
        }
    } else {
        #pragma unroll
        for (int mt = 0; mt < 2; ++mt)
            #pragma unroll
            for (int nt = 0; nt < 3; ++nt)
                #pragma unroll
                for (int r = 0; r < 4; ++r)
                    sCV[wn * 48 + nt * 16 + c16][wm * 32 + mt * 16 + 4 * g + r] =
                        (_Float16)(acc[mt][nt][r] + bb[nt]);
        __syncthreads();
        #pragma unroll
        for (int p = 0; p < 3; ++p) {
            int idx = t + p * 256;
            int n = idx >> 3, c8 = idx & 7;
            *(f16x8*)&VTh[((size_t)(bbat * NH + ((n0 + n) >> 6)) * DHD + ((n0 + n) & 63)) * LK
                          + l0 + c8 * 8] = *(const f16x8*)&sCV[n][c8 * 8];
        }
    }
}

// ---------------------------------------------------------------------------
// Kernel 2: attention, fp16 MFMA, q-tile 32 — verbatim the passing version.
// ---------------------------------------------------------------------------
__global__ __launch_bounds__(256) void attn_mfma(
    const _Float16* __restrict__ Qh, const _Float16* __restrict__ Kh,
    const _Float16* __restrict__ VTh, const float* __restrict__ maskp,
    const int* __restrict__ garc, const float* __restrict__ lnK,
    const float* __restrict__ lnV, float* __restrict__ outp)
{
    __shared__ __align__(16) _Float16 sP[32][520];
    __shared__ unsigned int sArcW[32 * 33];
    __shared__ float sTb[32][4];
    __shared__ float sMax[4][32];
    __shared__ float sStat[4][32][4];
    __shared__ float sFin[32][4];

    const int t = threadIdx.x;
    const int w = t >> 6, lane = t & 63, g = lane >> 4, c16 = lane & 15;
    const int bx = blockIdx.x;
    const int qt = bx & 15, h = (bx >> 4) % NH, b = bx / (16 * NH);
    const int q0 = qt * 32;
    const int kw = w * 128;

    const _Float16* Qb = Qh + ((size_t)(b * NH + h) * LQ) * DHD;
    const _Float16* Kb = Kh + ((size_t)(b * NH + h) * LK) * DHD;
    const _Float16* Vb = VTh + ((size_t)(b * NH + h) * DHD) * LK;

    const int* garcRow = garc + ((size_t)(b * LQ + q0)) * LK;
    #pragma unroll
    for (int p = 0; p < 4; ++p) {
        int idx = t + p * 256;
        int row = idx >> 5, wd = idx & 31;
        const int4* src = (const int4*)&garcRow[idx * 16];
        unsigned int u = 0;
        #pragma unroll
        for (int j = 0; j < 4; ++j) {
            int4 a4 = src[j];
            u |= (unsigned int)a4.x << (j * 8 + 0);
            u |= (unsigned int)a4.y << (j * 8 + 2);
            u |= (unsigned int)a4.z << (j * 8 + 4);
            u |= (unsigned int)a4.w << (j * 8 + 6);
        }
        sArcW[row * 33 + wd] = u;
    }
    if (t < 192) {
        int q = t / 6, rem = t % 6, rr = rem >> 1, part = rem & 1;
        const _Float16* qp = Qb + (size_t)(q0 + q) * DHD + part * 32;
        const float* lp = lnK + rr * 64 + part * 32;
        float a = 0.f;
        #pragma unroll
        for (int j = 0; j < 4; ++j) {
            f16x8 qv = *(const f16x8*)&qp[j * 8];
            float4 l0 = *(const float4*)&lp[j * 8];
            float4 l1 = *(const float4*)&lp[j * 8 + 4];
            a += (float)qv[0] * l0.x + (float)qv[1] * l0.y
               + (float)qv[2] * l0.z + (float)qv[3] * l0.w
               + (float)qv[4] * l1.x + (float)qv[5] * l1.y
               + (float)qv[6] * l1.z + (float)qv[7] * l1.w;
        }
        a += __shfl_xor(a, 1);
        if (part == 0) sTb[q][rr] = a;
    }
    f16x8 qa[2][2];
    #pragma unroll
    for (int qg = 0; qg < 2; ++qg) {
        qa[qg][0] = *(const f16x8*)&Qb[(q0 + 16 * qg + c16) * DHD + 8 * g];
        qa[qg][1] = *(const f16x8*)&Qb[(q0 + 16 * qg + c16) * DHD + 32 + 8 * g];
    }
    __syncthreads();

    f32x4 c[8][2];
    unsigned int aPk[2][2] = {{0u, 0u}, {0u, 0u}};
    float rm[2][4];
    const int sh = c16 * 2;
    #pragma unroll
    for (int qg = 0; qg < 2; ++qg)
        #pragma unroll
        for (int r = 0; r < 4; ++r) rm[qg][r] = -1e30f;
    #pragma unroll
    for (int tt = 0; tt < 8; ++tt) {
        int kg = kw + tt * 16 + c16;
        f16x8 kb0 = *(const f16x8*)&Kb[kg * DHD + 8 * g];
        f16x8 kb1 = *(const f16x8*)&Kb[kg * DHD + 32 + 8 * g];
        float mv = maskp[b * LK + kg];
        const int wb = w * 8 + tt;
        #pragma unroll
        for (int qg = 0; qg < 2; ++qg) {
            f32x4 s = (f32x4){0.f, 0.f, 0.f, 0.f};
            s = __builtin_amdgcn_mfma_f32_16x16x32_f16(qa[qg][0], kb0, s, 0, 0, 0);
            s = __builtin_amdgcn_mfma_f32_16x16x32_f16(qa[qg][1], kb1, s, 0, 0, 0);
            #pragma unroll
            for (int r = 0; r < 4; ++r) {
                int qrow = 16 * qg + 4 * g + r;
                unsigned int a = (sArcW[qrow * 33 + wb] >> sh) & 3u;
                aPk[qg][tt >> 2] |= a << ((tt & 3) * 8 + 2 * r);
                float sv = s[r] + sTb[qrow][a] + mv;
                s[r] = sv;
                rm[qg][r] = fmaxf(rm[qg][r], sv);
            }
            c[tt][qg] = s;
        }
    }

    #pragma unroll
    for (int qg = 0; qg < 2; ++qg)
        #pragma unroll
        for (int r = 0; r < 4; ++r) {
            float m = rm[qg][r];
            m = fmaxf(m, __shfl_xor(m, 1));
            m = fmaxf(m, __shfl_xor(m, 2));
            m = fmaxf(m, __shfl_xor(m, 4));
            m = fmaxf(m, __shfl_xor(m, 8));
            rm[qg][r] = m;
        }
    if (c16 == 0)
        #pragma unroll
        for (int qg = 0; qg < 2; ++qg)
            #pragma unroll
            for (int r = 0; r < 4; ++r) sMax[w][16 * qg + 4 * g + r] = rm[qg][r];
    __syncthreads();
    float Mr[2][4];
    #pragma unroll
    for (int qg = 0; qg < 2; ++qg)
        #pragma unroll
        for (int r = 0; r < 4; ++r) {
            int q = 16 * qg + 4 * g + r;
            Mr[qg][r] = fmaxf(fmaxf(sMax[0][q], sMax[1][q]),
                              fmaxf(sMax[2][q], sMax[3][q]));
        }

    float b0s[2][4], b1s[2][4], b2s[2][4];
    #pragma unroll
    for (int qg = 0; qg < 2; ++qg)
        #pragma unroll
        for (int r = 0; r < 4; ++r) {
            b0s[qg][r] = 0.f; b1s[qg][r] = 0.f; b2s[qg][r] = 0.f;
        }
    #pragma unroll
    for (int tt = 0; tt < 8; ++tt) {
        int kg = kw + tt * 16 + c16;
        #pragma unroll
        for (int qg = 0; qg < 2; ++qg)
            #pragma unroll
            for (int r = 0; r < 4; ++r) {
                float e = __expf(c[tt][qg][r] - Mr[qg][r]);
                unsigned int a = (aPk[qg][tt >> 2] >> ((tt & 3) * 8 + 2 * r)) & 3u;
                b0s[qg][r] += (a == 0u) ? e : 0.f;
                b1s[qg][r] += (a == 1u) ? e : 0.f;
                b2s[qg][r] += (a == 2u) ? e : 0.f;
                sP[16 * qg + 4 * g + r][kg] = (_Float16)e;
            }
    }
    #pragma unroll
    for (int qg = 0; qg < 2; ++qg)
        #pragma unroll
        for (int r = 0; r < 4; ++r) {
            #pragma unroll
            for (int o = 1; o < 16; o <<= 1) {
                b0s[qg][r] += __shfl_xor(b0s[qg][r], o);
                b1s[qg][r] += __shfl_xor(b1s[qg][r], o);
                b2s[qg][r] += __shfl_xor(b2s[qg][r], o);
            }
        }
    if (c16 == 0)
        #pragma unroll
        for (int qg = 0; qg < 2; ++qg)
            #pragma unroll
            for (int r = 0; r < 4; ++r) {
                float4 v = make_float4(b0s[qg][r], b1s[qg][r], b2s[qg][r], 0.f);
                *(float4*)&sStat[w][16 * qg + 4 * g + r][0] = v;
            }
    __syncthreads();
    if (t < 32) {
        float4 tot = make_float4(0.f, 0.f, 0.f, 0.f);
        #pragma unroll
        for (int ww = 0; ww < 4; ++ww) {
            float4 v = *(const float4*)&sStat[ww][t][0];
            tot.x += v.x; tot.y += v.y; tot.z += v.z;
        }
        sFin[t][0] = 1.0f / (tot.x + tot.y + tot.z);
        sFin[t][1] = tot.x; sFin[t][2] = tot.y; sFin[t][3] = tot.z;
    }

    f32x4 o[2] = {(f32x4){0.f, 0.f, 0.f, 0.f}, (f32x4){0.f, 0.f, 0.f, 0.f}};
    const _Float16* vrow = Vb + (size_t)(w * 16 + c16) * LK;
    #pragma unroll
    for (int ktile = 0; ktile < 16; ++ktile) {
        f16x8 vb = *(const f16x8*)&vrow[ktile * 32 + 8 * g];
        #pragma unroll
        for (int qg = 0; qg < 2; ++qg) {
            f16x8 pa = *(const f16x8*)&sP[16 * qg + c16][ktile * 32 + 8 * g];
            o[qg] = __builtin_amdgcn_mfma_f32_16x16x32_f16(pa, vb, o[qg], 0, 0, 0);
        }
    }
    __syncthreads();

    int d = w * 16 + c16;
    float lv0 = lnV[d], lv1 = lnV[64 + d], lv2 = lnV[128 + d];
    #pragma unroll
    for (int qg = 0; qg < 2; ++qg)
        #pragma unroll
        for (int r = 0; r < 4; ++r) {
            int q = 16 * qg + 4 * g + r;
            float4 st = *(const float4*)&sFin[q][0];
            float val = (o[qg][r] + st.y * lv0 + st.z * lv1 + st.w * lv2) * st.x;
            outp[((size_t)(b * LQ + q0 + q)) * DM + h * DHD + d] = val;
        }
}

// ---------------------------------------------------------------------------
extern "C" void kernel_launch(void* const* d_in, const int* in_sizes, int n_in,
                              void* d_out, int out_size, void* d_ws, size_t ws_size,
                              hipStream_t stream) {
    const float* hidden  = (const float*)d_in[0];
    const float* context = (const float*)d_in[1];
    const float* mask    = (const float*)d_in[2];
    const int*   garc    = (const int*)d_in[3];
    const float* Wq = (const float*)d_in[4];
    const float* bq = (const float*)d_in[5];
    const float* Wk = (const float*)d_in[6];
    const float* bk = (const float*)d_in[7];
    const float* Wv = (const float*)d_in[8];
    const float* bv = (const float*)d_in[9];
    const float* dpk  = (const float*)d_in[10];
    const float* dpv  = (const float*)d_in[11];
    const float* lnkg = (const float*)d_in[12];
    const float* lnkb = (const float*)d_in[13];
    const float* lnvg = (const float*)d_in[14];
    const float* lnvb = (const float*)d_in[15];
    float* out = (float*)d_out;

    const size_t perT = (size_t)NB * NH * LQ * DHD;   // 1,572,864 halves
    _Float16* Qh  = (_Float16*)d_ws;
    _Float16* Kh  = Qh + perT;
    _Float16* VTh = Kh + perT;
    _Float16* WT  = VTh + perT;                        // 3*768*768 halves
    float* lnK = (float*)(WT + (size_t)3 * DM * DM);
    float* lnV = lnK + 192;

    prep_kernel<<<433, 256, 0, stream>>>(Wq, Wk, Wv, dpk, dpv,
                                         lnkg, lnkb, lnvg, lnvb, WT, lnK, lnV);
    qkv_mfma<<<dim3(32, 24), 256, 0, stream>>>(hidden, context, WT,
                                               bq, bk, bv, Qh, Kh, VTh);
    attn_mfma<<<768, 256, 0, stream>>>(Qh, Kh, VTh, mask, garc, lnK, lnV, out);
}